// Round 1
// baseline (663.163 us; speedup 1.0000x reference)
//
#include <hip/hip_runtime.h>
#include <hip/hip_bf16.h>

typedef __attribute__((ext_vector_type(4))) float f32x4;
typedef __attribute__((ext_vector_type(8))) short s16x8;
typedef __attribute__((ext_vector_type(4))) short s16x4;

#define DEVINL __device__ __forceinline__

static constexpr int BB = 32, TT = 1024, DD = 512, EE = 256, VV = 50257, EXTRA = 200;
static constexpr int D2 = 1024;           // 2*D
static constexpr int VE = VV + EXTRA;     // 50457
static constexpr long MM = (long)BB * TT; // 32768

DEVINL unsigned short f2bf(float x) {
    union { float f; unsigned int u; } c; c.f = x;
    unsigned int u = c.u;
    u += 0x7fffu + ((u >> 16) & 1u);   // round-to-nearest-even
    return (unsigned short)(u >> 16);
}
DEVINL float sigmoidf_(float x) { return 1.0f / (1.0f + expf(-x)); }

// ---------------------------------------------------------------- K0: W_h^T -> bf16
__global__ void k_transpose_wh(const float* __restrict__ Wh, unsigned short* __restrict__ WhT) {
    __shared__ float tile[32][33];
    int n0 = blockIdx.x * 32, k0 = blockIdx.y * 32;
    int tx = threadIdx.x, ty = threadIdx.y;  // 32 x 8
    #pragma unroll
    for (int i = 0; i < 4; i++)
        tile[ty + i * 8][tx] = Wh[(long)(k0 + ty + i * 8) * D2 + n0 + tx];
    __syncthreads();
    #pragma unroll
    for (int i = 0; i < 4; i++)
        WhT[(long)(n0 + ty + i * 8) * D2 + k0 + tx] = f2bf(tile[tx][ty + i * 8]);
}

// ---------------------------------------------------------------- K1: x = [pcv|emb] @ W_gx + b_gx
__global__ void k_x(const int* __restrict__ dec_in, const float* __restrict__ pcv,
                    const float* __restrict__ embt, const float* __restrict__ Wgx,
                    const float* __restrict__ bgx, float* __restrict__ xbuf) {
    int b = blockIdx.x, e = threadIdx.x;  // 256 threads
    const float* embrow = embt + (long)dec_in[b] * EE;
    const float* pr = pcv + (long)b * D2;
    float acc = bgx[e];
    for (int k = 0; k < D2; k++) acc += pr[k] * Wgx[(long)k * EE + e];
    for (int k = 0; k < EE; k++) acc += embrow[k] * Wgx[(long)(D2 + k) * EE + e];
    xbuf[b * EE + e] = acc;
}

// ---------------------------------------------------------------- K2: LSTM cell
__global__ void k_lstm(const float* __restrict__ xbuf, const float* __restrict__ h0,
                       const float* __restrict__ c0, const float* __restrict__ Wih,
                       const float* __restrict__ Whh, const float* __restrict__ bih,
                       const float* __restrict__ bhh, float* __restrict__ h1o,
                       float* __restrict__ c1o, float* __restrict__ dechat) {
    int b = blockIdx.x, d = threadIdx.x;  // 512 threads
    float gi = bih[d] + bhh[d];
    float gf = bih[DD + d] + bhh[DD + d];
    float gg = bih[2 * DD + d] + bhh[2 * DD + d];
    float go = bih[3 * DD + d] + bhh[3 * DD + d];
    const float* xr = xbuf + b * EE;
    for (int k = 0; k < EE; k++) {
        float xv = xr[k]; const float* w = Wih + (long)k * 4 * DD;
        gi += xv * w[d]; gf += xv * w[DD + d]; gg += xv * w[2 * DD + d]; go += xv * w[3 * DD + d];
    }
    const float* hr = h0 + b * DD;
    for (int k = 0; k < DD; k++) {
        float hv = hr[k]; const float* w = Whh + (long)k * 4 * DD;
        gi += hv * w[d]; gf += hv * w[DD + d]; gg += hv * w[2 * DD + d]; go += hv * w[3 * DD + d];
    }
    float c1 = sigmoidf_(gf) * c0[b * DD + d] + sigmoidf_(gi) * tanhf(gg);
    float h1 = sigmoidf_(go) * tanhf(c1);
    h1o[b * DD + d] = h1; c1o[b * DD + d] = c1;
    dechat[b * D2 + d] = h1; dechat[b * D2 + DD + d] = c1;
}

// ---------------------------------------------------------------- K3: dec_feat = dec_hat @ W_s + b_s
__global__ void k_decfeat(const float* __restrict__ dechat, const float* __restrict__ Ws,
                          const float* __restrict__ bs, float* __restrict__ decfeat) {
    int b = blockIdx.x, j = blockIdx.y * 256 + threadIdx.x;
    const float* dr = dechat + b * D2;
    float acc = bs[j];
    for (int k = 0; k < D2; k++) acc += dr[k] * Ws[(long)k * D2 + j];
    decfeat[b * D2 + j] = acc;
}

// ---------------------------------------------------------------- K4: fused attention scores
// scores[m] = sum_j v[j]*tanh( (enc[m,:] @ W_h)[j] + dec_feat[b,j] + cov[m]*W_c[j] )
__global__ __launch_bounds__(512) void k_scores(
    const float* __restrict__ enc, const unsigned short* __restrict__ WhT,
    const float* __restrict__ decfeat, const float* __restrict__ cov,
    const float* __restrict__ Wc, const float* __restrict__ vvec,
    float* __restrict__ scores) {
    constexpr int PITCH = 80;  // ushorts per LDS row (64 + 16 pad -> 4-way conflict max)
    __shared__ unsigned short As[128 * PITCH];
    __shared__ unsigned short Bs[256 * PITCH];
    __shared__ float sred[4][128];
    const int tid = threadIdx.x;
    const int lane = tid & 63, wave = tid >> 6;
    const int wm = wave >> 2, wn = wave & 3;       // 2 x 4 waves over 128 x 256
    const int g = lane >> 4, c = lane & 15;
    const long m0 = (long)blockIdx.x * 128;
    const int bblk = (int)(m0 >> 10);              // 128 | 1024 -> whole block same batch row

    float sAcc[4][4];
    #pragma unroll
    for (int i = 0; i < 4; i++)
        #pragma unroll
        for (int r = 0; r < 4; r++) sAcc[i][r] = 0.f;

    for (int nt = 0; nt < 4; ++nt) {
        const int n0 = nt * 256;
        f32x4 acc[4][4];
        #pragma unroll
        for (int i = 0; i < 4; i++)
            #pragma unroll
            for (int j = 0; j < 4; j++) acc[i][j] = (f32x4){0.f, 0.f, 0.f, 0.f};

        for (int kt = 0; kt < 16; ++kt) {
            const int k0 = kt * 64;
            __syncthreads();
            // stage A: 128x64 f32 -> bf16 LDS [m][k]
            #pragma unroll
            for (int it = 0; it < 4; ++it) {
                int s = tid + it * 512;
                int m = s >> 4, kq = s & 15;
                f32x4 v4 = *(const f32x4*)(enc + (m0 + m) * 1024 + k0 + kq * 4);
                s16x4 h;
                h[0] = (short)f2bf(v4[0]); h[1] = (short)f2bf(v4[1]);
                h[2] = (short)f2bf(v4[2]); h[3] = (short)f2bf(v4[3]);
                *(s16x4*)&As[m * PITCH + kq * 4] = h;
            }
            // stage B: 256x64 bf16 from WhT[n][k]
            #pragma unroll
            for (int it = 0; it < 4; ++it) {
                int s = tid + it * 512;
                int n = s >> 3, kc = s & 7;
                s16x8 w = *(const s16x8*)(WhT + (long)(n0 + n) * 1024 + k0 + kc * 8);
                *(s16x8*)&Bs[n * PITCH + kc * 8] = w;
            }
            __syncthreads();
            #pragma unroll
            for (int kk = 0; kk < 2; ++kk) {
                const int krd = kk * 32 + g * 8;
                s16x8 af[4], bf_[4];
                #pragma unroll
                for (int i = 0; i < 4; i++) af[i] = *(const s16x8*)&As[(wm * 64 + i * 16 + c) * PITCH + krd];
                #pragma unroll
                for (int j = 0; j < 4; j++) bf_[j] = *(const s16x8*)&Bs[(wn * 64 + j * 16 + c) * PITCH + krd];
                #pragma unroll
                for (int i = 0; i < 4; i++)
                    #pragma unroll
                    for (int j = 0; j < 4; j++)
                        acc[i][j] = __builtin_amdgcn_mfma_f32_16x16x32_bf16(af[i], bf_[j], acc[i][j], 0, 0, 0);
            }
        }
        // fused epilogue for this n-chunk
        float dfv[4], wcv[4], vvj[4];
        #pragma unroll
        for (int j = 0; j < 4; j++) {
            int col = n0 + wn * 64 + j * 16 + c;
            dfv[j] = decfeat[bblk * D2 + col];
            wcv[j] = Wc[col];
            vvj[j] = vvec[col];
        }
        #pragma unroll
        for (int i = 0; i < 4; i++) {
            #pragma unroll
            for (int r = 0; r < 4; r++) {
                const long m = m0 + wm * 64 + i * 16 + g * 4 + r;
                const float covm = cov[m];
                float su = 0.f;
                #pragma unroll
                for (int j = 0; j < 4; j++) {
                    float e = acc[i][j][r] + dfv[j] + covm * wcv[j];
                    su += tanhf(e) * vvj[j];
                }
                // reduce the 16 columns held across this 16-lane segment
                su += __shfl_xor(su, 1); su += __shfl_xor(su, 2);
                su += __shfl_xor(su, 4); su += __shfl_xor(su, 8);
                sAcc[i][r] += su;
            }
        }
    }
    // combine the 4 column-waves (deterministic: disjoint stores, then sum)
    __syncthreads();
    if (c == 0) {
        #pragma unroll
        for (int i = 0; i < 4; i++)
            #pragma unroll
            for (int r = 0; r < 4; r++)
                sred[wn][wm * 64 + i * 16 + g * 4 + r] = sAcc[i][r];
    }
    __syncthreads();
    if (tid < 128)
        scores[m0 + tid] = sred[0][tid] + sred[1][tid] + sred[2][tid] + sred[3][tid];
}

// ---------------------------------------------------------------- K5: softmax + mask renorm
__global__ void k_softmax(const float* __restrict__ scores, const float* __restrict__ mask,
                          const float* __restrict__ cov, float* __restrict__ att,
                          float* __restrict__ covn) {
    int b = blockIdx.x, tid = threadIdx.x;  // 256 threads
    __shared__ float sm[8];
    float sv[4];
    float mx = -1e30f;
    #pragma unroll
    for (int i = 0; i < 4; i++) { sv[i] = scores[b * TT + tid + 256 * i]; mx = fmaxf(mx, sv[i]); }
    for (int o = 32; o; o >>= 1) mx = fmaxf(mx, __shfl_xor(mx, o));
    if ((tid & 63) == 0) sm[tid >> 6] = mx;
    __syncthreads();
    mx = fmaxf(fmaxf(sm[0], sm[1]), fmaxf(sm[2], sm[3]));
    __syncthreads();
    float e[4]; float s = 0.f;
    #pragma unroll
    for (int i = 0; i < 4; i++) { e[i] = expf(sv[i] - mx); s += e[i]; }
    for (int o = 32; o; o >>= 1) s += __shfl_xor(s, o);
    if ((tid & 63) == 0) sm[tid >> 6] = s;
    __syncthreads();
    s = sm[0] + sm[1] + sm[2] + sm[3];
    __syncthreads();
    float inv = 1.f / s;
    float am[4]; float s2 = 0.f;
    #pragma unroll
    for (int i = 0; i < 4; i++) { am[i] = e[i] * inv * mask[b * TT + tid + 256 * i]; s2 += am[i]; }
    for (int o = 32; o; o >>= 1) s2 += __shfl_xor(s2, o);
    if ((tid & 63) == 0) sm[tid >> 6] = s2;
    __syncthreads();
    s2 = sm[0] + sm[1] + sm[2] + sm[3];
    float inv2 = 1.f / s2;
    #pragma unroll
    for (int i = 0; i < 4; i++) {
        int t = tid + 256 * i;
        float a = am[i] * inv2;
        att[b * TT + t] = a;
        covn[b * TT + t] = cov[b * TT + t] + a;
    }
}

// ---------------------------------------------------------------- K6: context partials + reduce
__global__ void k_context(const float* __restrict__ enc, const float* __restrict__ att,
                          float* __restrict__ part) {
    int b = blockIdx.x, tc = blockIdx.y;  // 32 x 8
    int d4 = threadIdx.x;                 // 256 threads -> d = d4*4
    float a0 = 0, a1 = 0, a2 = 0, a3 = 0;
    const float* ab = att + b * TT;
    for (int t = tc * 128; t < tc * 128 + 128; ++t) {
        float a = ab[t];
        f32x4 ev = *(const f32x4*)(enc + ((long)b * TT + t) * D2 + d4 * 4);
        a0 += a * ev[0]; a1 += a * ev[1]; a2 += a * ev[2]; a3 += a * ev[3];
    }
    float* pp = part + (long)tc * BB * D2 + b * D2 + d4 * 4;
    pp[0] = a0; pp[1] = a1; pp[2] = a2; pp[3] = a3;
}

__global__ void k_ctxreduce(const float* __restrict__ part, float* __restrict__ ctx) {
    int i = blockIdx.x * 256 + threadIdx.x;  // 128 blocks covers 32*1024
    float s = 0.f;
    #pragma unroll
    for (int p = 0; p < 8; p++) s += part[(long)p * BB * D2 + i];
    ctx[i] = s;
}

// ---------------------------------------------------------------- K7a: p_gen
__global__ void k_pgen(const float* __restrict__ ctx, const float* __restrict__ dechat,
                       const float* __restrict__ xbuf, const float* __restrict__ Wpg,
                       const float* __restrict__ bpg, float* __restrict__ pgen) {
    int b = blockIdx.x, tid = threadIdx.x;  // 256 threads
    __shared__ float sm[8];
    float acc = 0.f;
    for (int k = tid; k < D2; k += 256)
        acc += ctx[b * D2 + k] * Wpg[k] + dechat[b * D2 + k] * Wpg[D2 + k];
    acc += xbuf[b * EE + tid] * Wpg[2 * D2 + tid];
    for (int o = 32; o; o >>= 1) acc += __shfl_xor(acc, o);
    if ((tid & 63) == 0) sm[tid >> 6] = acc;
    __syncthreads();
    if (tid == 0) {
        float t = sm[0] + sm[1] + sm[2] + sm[3];
        pgen[b] = sigmoidf_(t + bpg[0]);
    }
}

// ---------------------------------------------------------------- K7b: hidden = [h1|ctx] @ W_v1 + b_v1
__global__ void k_hidden(const float* __restrict__ h1, const float* __restrict__ ctx,
                         const float* __restrict__ Wv1, const float* __restrict__ bv1,
                         float* __restrict__ hidden) {
    int b = blockIdx.x, h = blockIdx.y * 256 + threadIdx.x;  // 32 x 2, 256
    float acc = bv1[h];
    for (int k = 0; k < DD; k++) acc += h1[b * DD + k] * Wv1[(long)k * DD + h];
    for (int k = 0; k < D2; k++) acc += ctx[b * D2 + k] * Wv1[(long)(DD + k) * DD + h];
    hidden[b * DD + h] = acc;
}

// ---------------------------------------------------------------- K8: logits = hidden @ W_v2 + b_v2
__global__ void k_logits(const float* __restrict__ hidden, const float* __restrict__ Wv2,
                         const float* __restrict__ bv2, float* __restrict__ logits) {
    int v = blockIdx.x * 256 + threadIdx.x;
    if (v >= VV) return;
    float acc[BB];
    float bv = bv2[v];
    #pragma unroll
    for (int b = 0; b < BB; b++) acc[b] = bv;
    for (int k = 0; k < DD; k++) {
        float w = Wv2[(long)k * VV + v];
        #pragma unroll
        for (int b = 0; b < BB; b++) acc[b] += hidden[b * DD + k] * w;  // uniform -> s_load
    }
    #pragma unroll
    for (int b = 0; b < BB; b++) logits[(long)b * VV + v] = acc[b];
}

// ---------------------------------------------------------------- K9: per-row max / sumexp
__global__ void k_rowstats(const float* __restrict__ logits, float* __restrict__ stats) {
    int b = blockIdx.x, tid = threadIdx.x;
    __shared__ float sm[8];
    const float* lr = logits + (long)b * VV;
    float mx = -1e30f;
    for (int v = tid; v < VV; v += 256) mx = fmaxf(mx, lr[v]);
    for (int o = 32; o; o >>= 1) mx = fmaxf(mx, __shfl_xor(mx, o));
    if ((tid & 63) == 0) sm[tid >> 6] = mx;
    __syncthreads();
    mx = fmaxf(fmaxf(sm[0], sm[1]), fmaxf(sm[2], sm[3]));
    __syncthreads();
    float s = 0.f;
    for (int v = tid; v < VV; v += 256) s += expf(lr[v] - mx);
    for (int o = 32; o; o >>= 1) s += __shfl_xor(s, o);
    if ((tid & 63) == 0) sm[tid >> 6] = s;
    __syncthreads();
    if (tid == 0) { stats[2 * b] = mx; stats[2 * b + 1] = sm[0] + sm[1] + sm[2] + sm[3]; }
}

// ---------------------------------------------------------------- K10: final vocab dist
__global__ void k_vocab_final(const float* __restrict__ logits, const float* __restrict__ stats,
                              const float* __restrict__ pgen, const float* __restrict__ extraz,
                              float* __restrict__ out0) {
    int b = blockIdx.x;
    int v = blockIdx.y * 256 + threadIdx.x;
    if (v >= VE) return;
    float r;
    if (v < VV) r = pgen[b] * expf(logits[(long)b * VV + v] - stats[2 * b]) / stats[2 * b + 1];
    else        r = extraz[b * EXTRA + (v - VV)];
    out0[(long)b * VE + v] = r;
}

// ---------------------------------------------------------------- K11: pointer scatter
__global__ void k_scatter(const int* __restrict__ eiv, const float* __restrict__ att,
                          const float* __restrict__ pgen, float* __restrict__ out0) {
    int b = blockIdx.x;
    int t = blockIdx.y * 256 + threadIdx.x;
    float a = (1.f - pgen[b]) * att[b * TT + t];
    atomicAdd(out0 + (long)b * VE + eiv[b * TT + t], a);
}

// ================================================================ host
extern "C" void kernel_launch(void* const* d_in, const int* in_sizes, int n_in,
                              void* d_out, int out_size, void* d_ws, size_t ws_size,
                              hipStream_t stream) {
    const int*   dec_in = (const int*)d_in[0];
    const float* h0     = (const float*)d_in[1];
    const float* c0     = (const float*)d_in[2];
    const float* enc    = (const float*)d_in[3];
    const float* mask   = (const float*)d_in[4];
    const float* pcv    = (const float*)d_in[5];
    const float* cov    = (const float*)d_in[6];
    const float* extraz = (const float*)d_in[7];
    const int*   eiv    = (const int*)d_in[8];
    /* d_in[9] = step (unused, training path) */
    const float* embt   = (const float*)d_in[10];
    const float* Wgx    = (const float*)d_in[11];
    const float* bgx    = (const float*)d_in[12];
    const float* Wih    = (const float*)d_in[13];
    const float* Whh    = (const float*)d_in[14];
    const float* bih    = (const float*)d_in[15];
    const float* bhh    = (const float*)d_in[16];
    const float* Wh     = (const float*)d_in[17];
    const float* Wc     = (const float*)d_in[18];
    const float* Ws     = (const float*)d_in[19];
    const float* bs     = (const float*)d_in[20];
    const float* vv     = (const float*)d_in[21];
    const float* Wpg    = (const float*)d_in[22];
    const float* bpg    = (const float*)d_in[23];
    const float* Wv1    = (const float*)d_in[24];
    const float* bv1    = (const float*)d_in[25];
    const float* Wv2    = (const float*)d_in[26];
    const float* bv2    = (const float*)d_in[27];

    float* out = (float*)d_out;
    float* out_vd  = out;
    float* out_h1  = out + (long)BB * VE;
    float* out_c1  = out_h1 + BB * DD;
    float* out_ctx = out_c1 + BB * DD;
    float* out_att = out_ctx + BB * D2;
    float* out_cov = out_att + BB * TT;

    char* p = (char*)d_ws;
    unsigned short* WhT = (unsigned short*)p;  p += (size_t)D2 * D2 * 2;     // 2 MB
    float* xbuf    = (float*)p;  p += (size_t)BB * EE * 4;
    float* dechat  = (float*)p;  p += (size_t)BB * D2 * 4;
    float* decfeat = (float*)p;  p += (size_t)BB * D2 * 4;
    float* scores  = (float*)p;  p += (size_t)MM * 4;
    float* pgen    = (float*)p;  p += 256;
    float* hidden  = (float*)p;  p += (size_t)BB * DD * 4;
    float* stats   = (float*)p;  p += 256;
    float* ctxpart = (float*)p;  p += (size_t)8 * BB * D2 * 4;               // 1 MB
    float* logits  = (float*)p;  p += (size_t)BB * VV * 4;                   // 6.4 MB

    k_transpose_wh<<<dim3(32, 32), dim3(32, 8), 0, stream>>>(Wh, WhT);
    k_x<<<BB, 256, 0, stream>>>(dec_in, pcv, embt, Wgx, bgx, xbuf);
    k_lstm<<<BB, 512, 0, stream>>>(xbuf, h0, c0, Wih, Whh, bih, bhh, out_h1, out_c1, dechat);
    k_decfeat<<<dim3(BB, 4), 256, 0, stream>>>(dechat, Ws, bs, decfeat);
    k_scores<<<256, 512, 0, stream>>>(enc, WhT, decfeat, cov, Wc, vv, scores);
    k_softmax<<<BB, 256, 0, stream>>>(scores, mask, cov, out_att, out_cov);
    k_context<<<dim3(BB, 8), 256, 0, stream>>>(enc, out_att, ctxpart);
    k_ctxreduce<<<(BB * D2) / 256, 256, 0, stream>>>(ctxpart, out_ctx);
    k_pgen<<<BB, 256, 0, stream>>>(out_ctx, dechat, xbuf, Wpg, bpg, pgen);
    k_hidden<<<dim3(BB, 2), 256, 0, stream>>>(out_h1, out_ctx, Wv1, bv1, hidden);
    k_logits<<<(VV + 255) / 256, 256, 0, stream>>>(hidden, Wv2, bv2, logits);
    k_rowstats<<<BB, 256, 0, stream>>>(logits, stats);
    k_vocab_final<<<dim3(BB, (VE + 255) / 256), 256, 0, stream>>>(logits, stats, pgen, extraz, out_vd);
    k_scatter<<<dim3(BB, 4), 256, 0, stream>>>(eiv, out_att, pgen, out_vd);
}

// Round 2
// 371.780 us; speedup vs baseline: 1.7838x; 1.7838x over previous
//
#include <hip/hip_runtime.h>
#include <hip/hip_bf16.h>

typedef __attribute__((ext_vector_type(4))) float f32x4;
typedef __attribute__((ext_vector_type(8))) short s16x8;

#define DEVINL __device__ __forceinline__

static constexpr int BB = 32, TT = 1024, DD = 512, EE = 256, VV = 50257, EXTRA = 200;
static constexpr int D2 = 1024;           // 2*D
static constexpr int VE = VV + EXTRA;     // 50457
static constexpr long MM = (long)BB * TT; // 32768

DEVINL unsigned short f2bf(float x) {
    union { float f; unsigned int u; } c; c.f = x;
    unsigned int u = c.u;
    u += 0x7fffu + ((u >> 16) & 1u);   // round-to-nearest-even
    return (unsigned short)(u >> 16);
}
DEVINL float sigmoidf_(float x) { return 1.0f / (1.0f + __expf(-x)); }
DEVINL float tanh_fast(float x) {
    x = fminf(15.f, fmaxf(-15.f, x));
    float e = __expf(2.f * x);
    return (e - 1.f) / (e + 1.f);
}
DEVINL void gl16(const void* g, void* l) {  // 16B global->LDS direct (dest: wave base + lane*16)
    __builtin_amdgcn_global_load_lds((__attribute__((address_space(1))) void*)g,
                                     (__attribute__((address_space(3))) void*)l, 16, 0, 0);
}

// ---------------------------------------------------------------- K0: W_h^T -> bf16, k-swizzled
// whtswz[n][k] = bf16(Wh[k ^ ((n&7)<<3)][n])   (XOR on k bits 3..5, G4 swizzle baked in)
__global__ void k_transpose_wh(const float* __restrict__ Wh, unsigned short* __restrict__ WhT) {
    __shared__ float tile[32][33];
    int n0 = blockIdx.x * 32, k0 = blockIdx.y * 32;
    int tx = threadIdx.x, ty = threadIdx.y;  // 32 x 8
    #pragma unroll
    for (int i = 0; i < 4; i++)
        tile[ty + i * 8][tx] = Wh[(long)(k0 + ty + i * 8) * D2 + n0 + tx];
    __syncthreads();
    #pragma unroll
    for (int i = 0; i < 4; i++) {
        int n = n0 + ty + i * 8;
        int kcol = (k0 + tx) ^ ((n & 7) << 3);
        WhT[(long)n * D2 + kcol] = f2bf(tile[tx][ty + i * 8]);
    }
}

// ---------------------------------------------------------------- K0b: enc f32 -> bf16, k-swizzled
// encswz[m][k] = bf16(enc[m][k ^ ((m&7)<<3)])
__global__ void k_enc2bf(const float* __restrict__ enc, unsigned short* __restrict__ dst) {
    long idx = (long)blockIdx.x * 256 + threadIdx.x;  // 16384 blocks
    int m  = (int)(idx >> 7);
    int k2 = (int)(idx & 127) * 8;
    int s  = (m & 7) << 3;
    const float* src = enc + (long)m * 1024 + (k2 ^ s);
    f32x4 a = *(const f32x4*)src;
    f32x4 b = *(const f32x4*)(src + 4);
    s16x8 h;
    h[0] = (short)f2bf(a[0]); h[1] = (short)f2bf(a[1]); h[2] = (short)f2bf(a[2]); h[3] = (short)f2bf(a[3]);
    h[4] = (short)f2bf(b[0]); h[5] = (short)f2bf(b[1]); h[6] = (short)f2bf(b[2]); h[7] = (short)f2bf(b[3]);
    *(s16x8*)(dst + (long)m * 1024 + k2) = h;
}

// ---------------------------------------------------------------- K1: x = [pcv|emb] @ W_gx + b_gx
__global__ void k_x(const int* __restrict__ dec_in, const float* __restrict__ pcv,
                    const float* __restrict__ embt, const float* __restrict__ Wgx,
                    const float* __restrict__ bgx, float* __restrict__ xbuf) {
    __shared__ float xs[1280];
    __shared__ float sred[4][64];
    int b = blockIdx.x, n0 = blockIdx.y * 64;     // grid (32,4)
    int tid = threadIdx.x, nl = tid & 63, ks = tid >> 6;
    long er = (long)dec_in[b] * EE;
    for (int i = tid; i < 1280; i += 256)
        xs[i] = (i < 1024) ? pcv[b * 1024 + i] : embt[er + i - 1024];
    __syncthreads();
    float acc = 0.f;
    for (int k = ks * 320; k < ks * 320 + 320; ++k)
        acc += xs[k] * Wgx[(long)k * EE + n0 + nl];
    sred[ks][nl] = acc;
    __syncthreads();
    if (tid < 64) {
        int n = n0 + tid;
        xbuf[b * EE + n] = sred[0][tid] + sred[1][tid] + sred[2][tid] + sred[3][tid] + bgx[n];
    }
}

// ---------------------------------------------------------------- K2: LSTM cell (fused k-split)
__global__ void k_lstm(const float* __restrict__ xbuf, const float* __restrict__ h0,
                       const float* __restrict__ c0, const float* __restrict__ Wih,
                       const float* __restrict__ Whh, const float* __restrict__ bih,
                       const float* __restrict__ bhh, float* __restrict__ h1o,
                       float* __restrict__ c1o, float* __restrict__ dechat) {
    __shared__ float xs[768];
    __shared__ float sred[4][4][64];
    int b = blockIdx.x, d0 = blockIdx.y * 64;     // grid (32,8)
    int tid = threadIdx.x, dl = tid & 63, ks = tid >> 6;
    for (int i = tid; i < 768; i += 256)
        xs[i] = (i < 256) ? xbuf[b * 256 + i] : h0[b * 512 + i - 256];
    __syncthreads();
    float a0 = 0, a1 = 0, a2 = 0, a3 = 0;
    for (int k = ks * 192; k < ks * 192 + 192; ++k) {
        float xv = xs[k];
        const float* wr = (k < 256) ? (Wih + (long)k * 2048) : (Whh + (long)(k - 256) * 2048);
        a0 += xv * wr[d0 + dl];       a1 += xv * wr[512 + d0 + dl];
        a2 += xv * wr[1024 + d0 + dl]; a3 += xv * wr[1536 + d0 + dl];
    }
    sred[0][ks][dl] = a0; sred[1][ks][dl] = a1; sred[2][ks][dl] = a2; sred[3][ks][dl] = a3;
    __syncthreads();
    if (tid < 64) {
        int d = d0 + tid;
        float gi = bih[d] + bhh[d];
        float gf = bih[512 + d] + bhh[512 + d];
        float gg = bih[1024 + d] + bhh[1024 + d];
        float go = bih[1536 + d] + bhh[1536 + d];
        #pragma unroll
        for (int s = 0; s < 4; s++) {
            gi += sred[0][s][tid]; gf += sred[1][s][tid];
            gg += sred[2][s][tid]; go += sred[3][s][tid];
        }
        float c1 = sigmoidf_(gf) * c0[b * 512 + d] + sigmoidf_(gi) * tanh_fast(gg);
        float h1 = sigmoidf_(go) * tanh_fast(c1);
        h1o[b * 512 + d] = h1; c1o[b * 512 + d] = c1;
        dechat[b * 1024 + d] = h1; dechat[b * 1024 + 512 + d] = c1;
    }
}

// ---------------------------------------------------------------- K3: dec_feat = dec_hat @ W_s + b_s
__global__ void k_decfeat(const float* __restrict__ dechat, const float* __restrict__ Ws,
                          const float* __restrict__ bs, float* __restrict__ decfeat) {
    __shared__ float xs[1024];
    __shared__ float sred[4][64];
    int b = blockIdx.x, n0 = blockIdx.y * 64;     // grid (32,16)
    int tid = threadIdx.x, nl = tid & 63, ks = tid >> 6;
    for (int i = tid; i < 1024; i += 256) xs[i] = dechat[b * 1024 + i];
    __syncthreads();
    float acc = 0.f;
    for (int k = ks * 256; k < ks * 256 + 256; ++k)
        acc += xs[k] * Ws[(long)k * 1024 + n0 + nl];
    sred[ks][nl] = acc;
    __syncthreads();
    if (tid < 64) {
        int n = n0 + tid;
        decfeat[b * 1024 + n] = sred[0][tid] + sred[1][tid] + sred[2][tid] + sred[3][tid] + bs[n];
    }
}

// ---------------------------------------------------------------- K4: fused attention scores (partial over nt)
// scorep[nt][m] = sum_{j in nt-chunk} v[j]*tanh( (enc@W_h)[m,j] + dec_feat[b,j] + cov[m]*W_c[j] )
__global__ __launch_bounds__(512) void k_scores(
    const unsigned short* __restrict__ encswz, const unsigned short* __restrict__ whtswz,
    const float* __restrict__ decfeat, const float* __restrict__ cov,
    const float* __restrict__ Wc, const float* __restrict__ vvec,
    float* __restrict__ scorep) {
    __shared__ unsigned short As[128 * 64];   // 16 KB, linear [r][64k], data pre-swizzled
    __shared__ unsigned short Bs[256 * 64];   // 32 KB
    __shared__ float sred[4][128];
    const int tid = threadIdx.x;
    const int lane = tid & 63, wave = tid >> 6;
    const int wid = __builtin_amdgcn_readfirstlane(wave);
    const int g = lane >> 4, c = lane & 15;
    const int wm = wave >> 2, wn = wave & 3;   // 2 x 4 waves over 128m x 256n

    // XCD-chunked decode: all 4 nt-blocks of one m-tile land on the same XCD, near in time
    const int bid = blockIdx.x;
    const int xcd = bid & 7, t = bid >> 3;
    const int mt = xcd * 32 + (t >> 2), nt = t & 3;
    const long m0 = (long)mt * 128;
    const int n0 = nt * 256;
    const int bblk = mt >> 3;                  // batch row (128*8 = 1024 rows per batch)

    // staging geometry: per wave A covers 16 rows (2 issues x 8), B covers 32 rows (4 issues x 8)
    const int arow = wid * 16 + (lane >> 3);
    const int axo  = (lane & 7) * 8;
    const int brow = wid * 32 + (lane >> 3);
    unsigned short* aBase = &As[wid * 1024];
    unsigned short* bBase = &Bs[wid * 2048];

    f32x4 acc[4][4];
    #pragma unroll
    for (int i = 0; i < 4; i++)
        #pragma unroll
        for (int j = 0; j < 4; j++) acc[i][j] = (f32x4){0.f, 0.f, 0.f, 0.f};

    const int sx = (c & 7) << 3;               // read-side swizzle (matches baked source swizzle)

    for (int kt = 0; kt < 16; ++kt) {
        const int k0 = kt * 64;
        __syncthreads();
        gl16(encswz + (m0 + arow) * 1024 + k0 + axo,       aBase);
        gl16(encswz + (m0 + arow + 8) * 1024 + k0 + axo,   aBase + 512);
        gl16(whtswz + (long)(n0 + brow) * 1024 + k0 + axo,        bBase);
        gl16(whtswz + (long)(n0 + brow + 8) * 1024 + k0 + axo,    bBase + 512);
        gl16(whtswz + (long)(n0 + brow + 16) * 1024 + k0 + axo,   bBase + 1024);
        gl16(whtswz + (long)(n0 + brow + 24) * 1024 + k0 + axo,   bBase + 1536);
        __syncthreads();                       // compiler drains vmcnt(0) here
        #pragma unroll
        for (int kk = 0; kk < 2; ++kk) {
            const int kse = (kk * 32 + g * 8) ^ sx;
            s16x8 af[4], bfj[4];
            #pragma unroll
            for (int i = 0; i < 4; i++) af[i] = *(const s16x8*)&As[(wm * 64 + i * 16 + c) * 64 + kse];
            #pragma unroll
            for (int j = 0; j < 4; j++) bfj[j] = *(const s16x8*)&Bs[(wn * 64 + j * 16 + c) * 64 + kse];
            #pragma unroll
            for (int i = 0; i < 4; i++)
                #pragma unroll
                for (int j = 0; j < 4; j++)
                    acc[i][j] = __builtin_amdgcn_mfma_f32_16x16x32_bf16(af[i], bfj[j], acc[i][j], 0, 0, 0);
        }
    }
    // fused epilogue: v-weighted tanh partial sums for this nt
    float dfv[4], wcv[4], vvj[4];
    #pragma unroll
    for (int j = 0; j < 4; j++) {
        int col = n0 + wn * 64 + j * 16 + c;
        dfv[j] = decfeat[bblk * D2 + col];
        wcv[j] = Wc[col];
        vvj[j] = vvec[col];
    }
    float sAcc[4][4];
    #pragma unroll
    for (int i = 0; i < 4; i++) {
        #pragma unroll
        for (int r = 0; r < 4; r++) {
            const long m = m0 + wm * 64 + i * 16 + g * 4 + r;
            const float covm = cov[m];
            float su = 0.f;
            #pragma unroll
            for (int j = 0; j < 4; j++) {
                float e = acc[i][j][r] + dfv[j] + covm * wcv[j];
                su += tanh_fast(e) * vvj[j];
            }
            su += __shfl_xor(su, 1); su += __shfl_xor(su, 2);
            su += __shfl_xor(su, 4); su += __shfl_xor(su, 8);
            sAcc[i][r] = su;
        }
    }
    if (c == 0) {
        #pragma unroll
        for (int i = 0; i < 4; i++)
            #pragma unroll
            for (int r = 0; r < 4; r++)
                sred[wn][wm * 64 + i * 16 + g * 4 + r] = sAcc[i][r];
    }
    __syncthreads();
    if (tid < 128)
        scorep[(long)nt * MM + m0 + tid] = sred[0][tid] + sred[1][tid] + sred[2][tid] + sred[3][tid];
}

// ---------------------------------------------------------------- K5: softmax + mask renorm
__global__ void k_softmax(const float* __restrict__ scorep, const float* __restrict__ mask,
                          const float* __restrict__ cov, float* __restrict__ att,
                          float* __restrict__ covn) {
    int b = blockIdx.x, tid = threadIdx.x;  // 256 threads
    __shared__ float sm[8];
    float sv[4];
    float mx = -1e30f;
    #pragma unroll
    for (int i = 0; i < 4; i++) {
        long idx = (long)b * TT + tid + 256 * i;
        sv[i] = scorep[idx] + scorep[MM + idx] + scorep[2 * MM + idx] + scorep[3 * MM + idx];
        mx = fmaxf(mx, sv[i]);
    }
    for (int o = 32; o; o >>= 1) mx = fmaxf(mx, __shfl_xor(mx, o));
    if ((tid & 63) == 0) sm[tid >> 6] = mx;
    __syncthreads();
    mx = fmaxf(fmaxf(sm[0], sm[1]), fmaxf(sm[2], sm[3]));
    __syncthreads();
    float e[4]; float s = 0.f;
    #pragma unroll
    for (int i = 0; i < 4; i++) { e[i] = __expf(sv[i] - mx); s += e[i]; }
    for (int o = 32; o; o >>= 1) s += __shfl_xor(s, o);
    if ((tid & 63) == 0) sm[tid >> 6] = s;
    __syncthreads();
    s = sm[0] + sm[1] + sm[2] + sm[3];
    __syncthreads();
    float inv = 1.f / s;
    float am[4]; float s2 = 0.f;
    #pragma unroll
    for (int i = 0; i < 4; i++) { am[i] = e[i] * inv * mask[b * TT + tid + 256 * i]; s2 += am[i]; }
    for (int o = 32; o; o >>= 1) s2 += __shfl_xor(s2, o);
    if ((tid & 63) == 0) sm[tid >> 6] = s2;
    __syncthreads();
    s2 = sm[0] + sm[1] + sm[2] + sm[3];
    float inv2 = 1.f / s2;
    #pragma unroll
    for (int i = 0; i < 4; i++) {
        int t = tid + 256 * i;
        float a = am[i] * inv2;
        att[b * TT + t] = a;
        covn[b * TT + t] = cov[b * TT + t] + a;
    }
}

// ---------------------------------------------------------------- K6: context partials + reduce
__global__ void k_context(const float* __restrict__ enc, const float* __restrict__ att,
                          float* __restrict__ part) {
    int b = blockIdx.x, tc = blockIdx.y;  // grid (32,16)
    int d4 = threadIdx.x;                 // 256 threads -> d = d4*4
    float a0 = 0, a1 = 0, a2 = 0, a3 = 0;
    const float* ab = att + b * TT;
    for (int t = tc * 64; t < tc * 64 + 64; ++t) {
        float a = ab[t];
        f32x4 ev = *(const f32x4*)(enc + ((long)b * TT + t) * D2 + d4 * 4);
        a0 += a * ev[0]; a1 += a * ev[1]; a2 += a * ev[2]; a3 += a * ev[3];
    }
    float* pp = part + (long)tc * BB * D2 + b * D2 + d4 * 4;
    pp[0] = a0; pp[1] = a1; pp[2] = a2; pp[3] = a3;
}

__global__ void k_ctxreduce(const float* __restrict__ part, float* __restrict__ ctx) {
    int i = blockIdx.x * 256 + threadIdx.x;  // 128 blocks
    float s = 0.f;
    #pragma unroll
    for (int p = 0; p < 16; p++) s += part[(long)p * BB * D2 + i];
    ctx[i] = s;
}

// ---------------------------------------------------------------- K7a: p_gen
__global__ void k_pgen(const float* __restrict__ ctx, const float* __restrict__ dechat,
                       const float* __restrict__ xbuf, const float* __restrict__ Wpg,
                       const float* __restrict__ bpg, float* __restrict__ pgen) {
    int b = blockIdx.x, tid = threadIdx.x;  // 256 threads
    __shared__ float sm[8];
    float acc = 0.f;
    for (int k = tid; k < D2; k += 256)
        acc += ctx[b * D2 + k] * Wpg[k] + dechat[b * D2 + k] * Wpg[D2 + k];
    acc += xbuf[b * EE + tid] * Wpg[2 * D2 + tid];
    for (int o = 32; o; o >>= 1) acc += __shfl_xor(acc, o);
    if ((tid & 63) == 0) sm[tid >> 6] = acc;
    __syncthreads();
    if (tid == 0) {
        float t = sm[0] + sm[1] + sm[2] + sm[3];
        pgen[b] = sigmoidf_(t + bpg[0]);
    }
}

// ---------------------------------------------------------------- K7b: hidden = [h1|ctx] @ W_v1 + b_v1
__global__ void k_hidden(const float* __restrict__ h1, const float* __restrict__ ctx,
                         const float* __restrict__ Wv1, const float* __restrict__ bv1,
                         float* __restrict__ hidden) {
    __shared__ float xs[1536];
    __shared__ float sred[4][64];
    int b = blockIdx.x, n0 = blockIdx.y * 64;   // grid (32,8)
    int tid = threadIdx.x, nl = tid & 63, ks = tid >> 6;
    for (int i = tid; i < 1536; i += 256)
        xs[i] = (i < 512) ? h1[b * 512 + i] : ctx[b * 1024 + i - 512];
    __syncthreads();
    float acc = 0.f;
    for (int k = ks * 384; k < ks * 384 + 384; ++k)
        acc += xs[k] * Wv1[(long)k * 512 + n0 + nl];
    sred[ks][nl] = acc;
    __syncthreads();
    if (tid < 64) {
        int n = n0 + tid;
        hidden[b * 512 + n] = sred[0][tid] + sred[1][tid] + sred[2][tid] + sred[3][tid] + bv1[n];
    }
}

// ---------------------------------------------------------------- K8: logits = hidden @ W_v2 + b_v2
// block: 256 thr = 4 waves (b-groups of 8), 128 v-cols; hidden transposed in LDS (broadcast b128)
__global__ __launch_bounds__(256) void k_logits(const float* __restrict__ hidden,
                                                const float* __restrict__ Wv2,
                                                const float* __restrict__ bv2,
                                                float* __restrict__ logits) {
    __shared__ float hs[512 * 36];   // hs[k*36 + b] = hidden[b][k]; pad 36 -> 16B-aligned reads
    int tid = threadIdx.x;
    for (int idx = tid; idx < 16384; idx += 256) {
        int b = idx >> 9, k = idx & 511;
        hs[k * 36 + b] = hidden[idx];
    }
    __syncthreads();
    int v0 = blockIdx.x * 128;       // grid 393
    int l = tid & 63;
    int bg = (tid >> 6) * 8;
    if (v0 + 128 <= VV) {
        int v = v0 + l;
        float accA[8], accB[8];
        float bvA = bv2[v], bvB = bv2[v + 64];
        #pragma unroll
        for (int i = 0; i < 8; i++) { accA[i] = bvA; accB[i] = bvB; }
        #pragma unroll 4
        for (int k = 0; k < 512; ++k) {
            float wA = Wv2[(long)k * VV + v];
            float wB = Wv2[(long)k * VV + v + 64];
            f32x4 ha = *(const f32x4*)&hs[k * 36 + bg];
            f32x4 hb = *(const f32x4*)&hs[k * 36 + bg + 4];
            accA[0] += ha[0] * wA; accA[1] += ha[1] * wA; accA[2] += ha[2] * wA; accA[3] += ha[3] * wA;
            accA[4] += hb[0] * wA; accA[5] += hb[1] * wA; accA[6] += hb[2] * wA; accA[7] += hb[3] * wA;
            accB[0] += ha[0] * wB; accB[1] += ha[1] * wB; accB[2] += ha[2] * wB; accB[3] += ha[3] * wB;
            accB[4] += hb[0] * wB; accB[5] += hb[1] * wB; accB[6] += hb[2] * wB; accB[7] += hb[3] * wB;
        }
        #pragma unroll
        for (int i = 0; i < 8; i++) {
            logits[(long)(bg + i) * VV + v] = accA[i];
            logits[(long)(bg + i) * VV + v + 64] = accB[i];
        }
    } else {
        #pragma unroll
        for (int half = 0; half < 2; ++half) {
            int v = v0 + half * 64 + l;
            if (v >= VV) continue;
            float acc[8];
            float bv = bv2[v];
            #pragma unroll
            for (int i = 0; i < 8; i++) acc[i] = bv;
            for (int k = 0; k < 512; ++k) {
                float w = Wv2[(long)k * VV + v];
                f32x4 ha = *(const f32x4*)&hs[k * 36 + bg];
                f32x4 hb = *(const f32x4*)&hs[k * 36 + bg + 4];
                acc[0] += ha[0] * w; acc[1] += ha[1] * w; acc[2] += ha[2] * w; acc[3] += ha[3] * w;
                acc[4] += hb[0] * w; acc[5] += hb[1] * w; acc[6] += hb[2] * w; acc[7] += hb[3] * w;
            }
            #pragma unroll
            for (int i = 0; i < 8; i++) logits[(long)(bg + i) * VV + v] = acc[i];
        }
    }
}

// ---------------------------------------------------------------- K9: per-row max / sumexp
__global__ void k_rowstats(const float* __restrict__ logits, float* __restrict__ stats) {
    int b = blockIdx.x, tid = threadIdx.x;
    __shared__ float sm[8];
    const float* lr = logits + (long)b * VV;
    float mx = -1e30f;
    for (int v = tid; v < VV; v += 256) mx = fmaxf(mx, lr[v]);
    for (int o = 32; o; o >>= 1) mx = fmaxf(mx, __shfl_xor(mx, o));
    if ((tid & 63) == 0) sm[tid >> 6] = mx;
    __syncthreads();
    mx = fmaxf(fmaxf(sm[0], sm[1]), fmaxf(sm[2], sm[3]));
    __syncthreads();
    float s = 0.f;
    for (int v = tid; v < VV; v += 256) s += __expf(lr[v] - mx);
    for (int o = 32; o; o >>= 1) s += __shfl_xor(s, o);
    if ((tid & 63) == 0) sm[tid >> 6] = s;
    __syncthreads();
    if (tid == 0) { stats[2 * b] = mx; stats[2 * b + 1] = sm[0] + sm[1] + sm[2] + sm[3]; }
}

// ---------------------------------------------------------------- K10: final vocab dist
__global__ void k_vocab_final(const float* __restrict__ logits, const float* __restrict__ stats,
                              const float* __restrict__ pgen, const float* __restrict__ extraz,
                              float* __restrict__ out0) {
    int b = blockIdx.x;
    int v = blockIdx.y * 256 + threadIdx.x;
    if (v >= VE) return;
    float r;
    if (v < VV) r = pgen[b] * __expf(logits[(long)b * VV + v] - stats[2 * b]) / stats[2 * b + 1];
    else        r = extraz[b * EXTRA + (v - VV)];
    out0[(long)b * VE + v] = r;
}

// ---------------------------------------------------------------- K11: pointer scatter
__global__ void k_scatter(const int* __restrict__ eiv, const float* __restrict__ att,
                          const float* __restrict__ pgen, float* __restrict__ out0) {
    int b = blockIdx.x;
    int t = blockIdx.y * 256 + threadIdx.x;
    float a = (1.f - pgen[b]) * att[b * TT + t];
    atomicAdd(out0 + (long)b * VE + eiv[b * TT + t], a);
}

// ================================================================ host
extern "C" void kernel_launch(void* const* d_in, const int* in_sizes, int n_in,
                              void* d_out, int out_size, void* d_ws, size_t ws_size,
                              hipStream_t stream) {
    const int*   dec_in = (const int*)d_in[0];
    const float* h0     = (const float*)d_in[1];
    const float* c0     = (const float*)d_in[2];
    const float* enc    = (const float*)d_in[3];
    const float* mask   = (const float*)d_in[4];
    const float* pcv    = (const float*)d_in[5];
    const float* cov    = (const float*)d_in[6];
    const float* extraz = (const float*)d_in[7];
    const int*   eiv    = (const int*)d_in[8];
    /* d_in[9] = step (unused, training path) */
    const float* embt   = (const float*)d_in[10];
    const float* Wgx    = (const float*)d_in[11];
    const float* bgx    = (const float*)d_in[12];
    const float* Wih    = (const float*)d_in[13];
    const float* Whh    = (const float*)d_in[14];
    const float* bih    = (const float*)d_in[15];
    const float* bhh    = (const float*)d_in[16];
    const float* Wh     = (const float*)d_in[17];
    const float* Wc     = (const float*)d_in[18];
    const float* Ws     = (const float*)d_in[19];
    const float* bs     = (const float*)d_in[20];
    const float* vv     = (const float*)d_in[21];
    const float* Wpg    = (const float*)d_in[22];
    const float* bpg    = (const float*)d_in[23];
    const float* Wv1    = (const float*)d_in[24];
    const float* bv1    = (const float*)d_in[25];
    const float* Wv2    = (const float*)d_in[26];
    const float* bv2    = (const float*)d_in[27];

    float* out = (float*)d_out;
    float* out_vd  = out;
    float* out_h1  = out + (long)BB * VE;
    float* out_c1  = out_h1 + BB * DD;
    float* out_ctx = out_c1 + BB * DD;
    float* out_att = out_ctx + BB * D2;
    float* out_cov = out_att + BB * TT;

    // persistent region
    char* p = (char*)d_ws;
    unsigned short* whtswz = (unsigned short*)p; p += (size_t)D2 * D2 * 2;      // 2 MB
    float* xbuf    = (float*)p;  p += (size_t)BB * EE * 4;
    float* dechat  = (float*)p;  p += (size_t)BB * D2 * 4;
    float* decfeat = (float*)p;  p += (size_t)BB * D2 * 4;
    float* scorep  = (float*)p;  p += (size_t)4 * MM * 4;                        // 512 KB
    float* pgen    = (float*)p;  p += 256;
    float* hidden  = (float*)p;  p += (size_t)BB * DD * 4;
    float* stats   = (float*)p;  p += 256;
    unsigned short* encswz = (unsigned short*)p;                                 // 67.1 MB
    // overlap region (encswz is dead after k_scores):
    float* ctxpart = (float*)p;                                                  // 2 MB
    float* logits  = (float*)(p + (size_t)16 * BB * D2 * 4);                     // 6.43 MB

    k_transpose_wh<<<dim3(32, 32), dim3(32, 8), 0, stream>>>(Wh, whtswz);
    k_enc2bf<<<16384, 256, 0, stream>>>(enc, encswz);
    k_x<<<dim3(BB, 4), 256, 0, stream>>>(dec_in, pcv, embt, Wgx, bgx, xbuf);
    k_lstm<<<dim3(BB, 8), 256, 0, stream>>>(xbuf, h0, c0, Wih, Whh, bih, bhh, out_h1, out_c1, dechat);
    k_decfeat<<<dim3(BB, 16), 256, 0, stream>>>(dechat, Ws, bs, decfeat);
    k_scores<<<1024, 512, 0, stream>>>(encswz, whtswz, decfeat, cov, Wc, vv, scorep);
    k_softmax<<<BB, 256, 0, stream>>>(scorep, mask, cov, out_att, out_cov);
    k_context<<<dim3(BB, 16), 256, 0, stream>>>(enc, out_att, ctxpart);
    k_ctxreduce<<<(BB * D2) / 256, 256, 0, stream>>>(ctxpart, out_ctx);
    k_pgen<<<BB, 256, 0, stream>>>(out_ctx, dechat, xbuf, Wpg, bpg, pgen);
    k_hidden<<<dim3(BB, 8), 256, 0, stream>>>(out_h1, out_ctx, Wv1, bv1, hidden);
    k_logits<<<393, 256, 0, stream>>>(hidden, Wv2, bv2, logits);
    k_rowstats<<<BB, 256, 0, stream>>>(logits, stats);
    k_vocab_final<<<dim3(BB, (VE + 255) / 256), 256, 0, stream>>>(logits, stats, pgen, extraz, out_vd);
    k_scatter<<<dim3(BB, 4), 256, 0, stream>>>(eiv, out_att, pgen, out_vd);
}

// Round 3
// 355.159 us; speedup vs baseline: 1.8672x; 1.0468x over previous
//
#include <hip/hip_runtime.h>
#include <hip/hip_bf16.h>

typedef __attribute__((ext_vector_type(4))) float f32x4;
typedef __attribute__((ext_vector_type(8))) short s16x8;

#define DEVINL __device__ __forceinline__

static constexpr int BB = 32, TT = 1024, DD = 512, EE = 256, VV = 50257, EXTRA = 200;
static constexpr int D2 = 1024;           // 2*D
static constexpr int VE = VV + EXTRA;     // 50457
static constexpr long MM = (long)BB * TT; // 32768

DEVINL unsigned short f2bf(float x) {
    union { float f; unsigned int u; } c; c.f = x;
    unsigned int u = c.u;
    u += 0x7fffu + ((u >> 16) & 1u);   // round-to-nearest-even
    return (unsigned short)(u >> 16);
}
DEVINL float sigmoidf_(float x) { return 1.0f / (1.0f + __expf(-x)); }
DEVINL float tanh_fast(float x) {
    x = fminf(15.f, fmaxf(-15.f, x));
    float e = __expf(2.f * x);
    return (e - 1.f) / (e + 1.f);
}
DEVINL void gl16(const void* g, void* l) {  // 16B global->LDS direct (dest: wave base + lane*16)
    __builtin_amdgcn_global_load_lds((__attribute__((address_space(1))) void*)g,
                                     (__attribute__((address_space(3))) void*)l, 16, 0, 0);
}

// ---------------------------------------------------------------- K0: W_h^T -> bf16, k-swizzled
// whtswz[n][k] = bf16(Wh[k ^ ((n&7)<<3)][n])   (XOR on k bits 3..5, G4 swizzle baked in)
__global__ void k_transpose_wh(const float* __restrict__ Wh, unsigned short* __restrict__ WhT) {
    __shared__ float tile[32][33];
    int n0 = blockIdx.x * 32, k0 = blockIdx.y * 32;
    int tx = threadIdx.x, ty = threadIdx.y;  // 32 x 8
    #pragma unroll
    for (int i = 0; i < 4; i++)
        tile[ty + i * 8][tx] = Wh[(long)(k0 + ty + i * 8) * D2 + n0 + tx];
    __syncthreads();
    #pragma unroll
    for (int i = 0; i < 4; i++) {
        int n = n0 + ty + i * 8;
        int kcol = (k0 + tx) ^ ((n & 7) << 3);
        WhT[(long)n * D2 + kcol] = f2bf(tile[tx][ty + i * 8]);
    }
}

// ---------------------------------------------------------------- K1: x = [pcv|emb] @ W_gx + b_gx
__global__ void k_x(const int* __restrict__ dec_in, const float* __restrict__ pcv,
                    const float* __restrict__ embt, const float* __restrict__ Wgx,
                    const float* __restrict__ bgx, float* __restrict__ xbuf) {
    __shared__ float xs[1280];
    __shared__ float sred[4][64];
    int b = blockIdx.x, n0 = blockIdx.y * 64;     // grid (32,4)
    int tid = threadIdx.x, nl = tid & 63, ks = tid >> 6;
    long er = (long)dec_in[b] * EE;
    for (int i = tid; i < 1280; i += 256)
        xs[i] = (i < 1024) ? pcv[b * 1024 + i] : embt[er + i - 1024];
    __syncthreads();
    float acc = 0.f;
    for (int k = ks * 320; k < ks * 320 + 320; ++k)
        acc += xs[k] * Wgx[(long)k * EE + n0 + nl];
    sred[ks][nl] = acc;
    __syncthreads();
    if (tid < 64) {
        int n = n0 + tid;
        xbuf[b * EE + n] = sred[0][tid] + sred[1][tid] + sred[2][tid] + sred[3][tid] + bgx[n];
    }
}

// ---------------------------------------------------------------- K2: LSTM cell (fused k-split)
__global__ void k_lstm(const float* __restrict__ xbuf, const float* __restrict__ h0,
                       const float* __restrict__ c0, const float* __restrict__ Wih,
                       const float* __restrict__ Whh, const float* __restrict__ bih,
                       const float* __restrict__ bhh, float* __restrict__ h1o,
                       float* __restrict__ c1o, float* __restrict__ dechat) {
    __shared__ float xs[768];
    __shared__ float sred[4][4][64];
    int b = blockIdx.x, d0 = blockIdx.y * 64;     // grid (32,8)
    int tid = threadIdx.x, dl = tid & 63, ks = tid >> 6;
    for (int i = tid; i < 768; i += 256)
        xs[i] = (i < 256) ? xbuf[b * 256 + i] : h0[b * 512 + i - 256];
    __syncthreads();
    float a0 = 0, a1 = 0, a2 = 0, a3 = 0;
    for (int k = ks * 192; k < ks * 192 + 192; ++k) {
        float xv = xs[k];
        const float* wr = (k < 256) ? (Wih + (long)k * 2048) : (Whh + (long)(k - 256) * 2048);
        a0 += xv * wr[d0 + dl];       a1 += xv * wr[512 + d0 + dl];
        a2 += xv * wr[1024 + d0 + dl]; a3 += xv * wr[1536 + d0 + dl];
    }
    sred[0][ks][dl] = a0; sred[1][ks][dl] = a1; sred[2][ks][dl] = a2; sred[3][ks][dl] = a3;
    __syncthreads();
    if (tid < 64) {
        int d = d0 + tid;
        float gi = bih[d] + bhh[d];
        float gf = bih[512 + d] + bhh[512 + d];
        float gg = bih[1024 + d] + bhh[1024 + d];
        float go = bih[1536 + d] + bhh[1536 + d];
        #pragma unroll
        for (int s = 0; s < 4; s++) {
            gi += sred[0][s][tid]; gf += sred[1][s][tid];
            gg += sred[2][s][tid]; go += sred[3][s][tid];
        }
        float c1 = sigmoidf_(gf) * c0[b * 512 + d] + sigmoidf_(gi) * tanh_fast(gg);
        float h1 = sigmoidf_(go) * tanh_fast(c1);
        h1o[b * 512 + d] = h1; c1o[b * 512 + d] = c1;
        dechat[b * 1024 + d] = h1; dechat[b * 1024 + 512 + d] = c1;
    }
}

// ---------------------------------------------------------------- K3: dec_feat = dec_hat @ W_s + b_s
__global__ void k_decfeat(const float* __restrict__ dechat, const float* __restrict__ Ws,
                          const float* __restrict__ bs, float* __restrict__ decfeat) {
    __shared__ float xs[1024];
    __shared__ float sred[4][64];
    int b = blockIdx.x, n0 = blockIdx.y * 64;     // grid (32,16)
    int tid = threadIdx.x, nl = tid & 63, ks = tid >> 6;
    for (int i = tid; i < 1024; i += 256) xs[i] = dechat[b * 1024 + i];
    __syncthreads();
    float acc = 0.f;
    for (int k = ks * 256; k < ks * 256 + 256; ++k)
        acc += xs[k] * Ws[(long)k * 1024 + n0 + nl];
    sred[ks][nl] = acc;
    __syncthreads();
    if (tid < 64) {
        int n = n0 + tid;
        decfeat[b * 1024 + n] = sred[0][tid] + sred[1][tid] + sred[2][tid] + sred[3][tid] + bs[n];
    }
}

// ---------------------------------------------------------------- K4: fused attention scores (partial over nt)
// A (enc) read f32 directly, converted in-kernel, swizzle-stored to LDS.
// scorep[nt][m] = sum_{j in nt-chunk} v[j]*tanh( (enc@W_h)[m,j] + dec_feat[b,j] + cov[m]*W_c[j] )
__global__ __launch_bounds__(512) void k_scores(
    const float* __restrict__ enc, const unsigned short* __restrict__ whtswz,
    const float* __restrict__ decfeat, const float* __restrict__ cov,
    const float* __restrict__ Wc, const float* __restrict__ vvec,
    float* __restrict__ scorep) {
    __shared__ unsigned short As[128 * 64];   // 16 KB, [r][64k] with XOR(k,(r&7)<<3) baked
    __shared__ unsigned short Bs[256 * 64];   // 32 KB, linear (source pre-swizzled)
    __shared__ float sred[4][128];
    const int tid = threadIdx.x;
    const int lane = tid & 63, wave = tid >> 6;
    const int wid = __builtin_amdgcn_readfirstlane(wave);
    const int g = lane >> 4, c = lane & 15;
    const int wm = wave >> 2, wn = wave & 3;   // 2 x 4 waves over 128m x 256n

    // XCD-chunked decode: the 4 nt-blocks of one m-tile are adjacent on the same XCD
    const int bid = blockIdx.x;
    const int xcd = bid & 7, t = bid >> 3;
    const int mt = xcd * 32 + (t >> 2), nt = t & 3;
    const long m0 = (long)mt * 128;
    const int n0 = nt * 256;
    const int bblk = mt >> 3;                  // batch row

    // A staging mapping: thread -> row r (4 thr/row), 16-float chunk c16
    const int ar = tid >> 2, ac16 = (tid & 3) * 16;
    const int asx = (ar & 7) << 3;
    // B staging: per wave 32 rows via 4 gl16
    const int brow = wid * 32 + (lane >> 3);
    const int bxo  = (lane & 7) * 8;
    unsigned short* bBase = &Bs[wid * 2048];

    f32x4 acc[4][4];
    #pragma unroll
    for (int i = 0; i < 4; i++)
        #pragma unroll
        for (int j = 0; j < 4; j++) acc[i][j] = (f32x4){0.f, 0.f, 0.f, 0.f};

    const int sx = (c & 7) << 3;               // read-side swizzle

    for (int kt = 0; kt < 16; ++kt) {
        const int k0 = kt * 64;
        __syncthreads();
        // B: global_load_lds from pre-swizzled weights (linear dest)
        gl16(whtswz + (long)(n0 + brow) * 1024 + k0 + bxo,        bBase);
        gl16(whtswz + (long)(n0 + brow + 8) * 1024 + k0 + bxo,    bBase + 512);
        gl16(whtswz + (long)(n0 + brow + 16) * 1024 + k0 + bxo,   bBase + 1024);
        gl16(whtswz + (long)(n0 + brow + 24) * 1024 + k0 + bxo,   bBase + 1536);
        // A: f32 -> bf16 reg-staged with swizzled ds_write (16 floats/thread)
        {
            const float* src = enc + (m0 + ar) * 1024 + k0 + ac16;
            f32x4 a0 = ((const f32x4*)src)[0];
            f32x4 a1 = ((const f32x4*)src)[1];
            f32x4 a2 = ((const f32x4*)src)[2];
            f32x4 a3 = ((const f32x4*)src)[3];
            s16x8 p0, p1;
            p0[0] = (short)f2bf(a0[0]); p0[1] = (short)f2bf(a0[1]);
            p0[2] = (short)f2bf(a0[2]); p0[3] = (short)f2bf(a0[3]);
            p0[4] = (short)f2bf(a1[0]); p0[5] = (short)f2bf(a1[1]);
            p0[6] = (short)f2bf(a1[2]); p0[7] = (short)f2bf(a1[3]);
            p1[0] = (short)f2bf(a2[0]); p1[1] = (short)f2bf(a2[1]);
            p1[2] = (short)f2bf(a2[2]); p1[3] = (short)f2bf(a2[3]);
            p1[4] = (short)f2bf(a3[0]); p1[5] = (short)f2bf(a3[1]);
            p1[6] = (short)f2bf(a3[2]); p1[7] = (short)f2bf(a3[3]);
            *(s16x8*)&As[ar * 64 + (ac16 ^ asx)]       = p0;
            *(s16x8*)&As[ar * 64 + ((ac16 + 8) ^ asx)] = p1;
        }
        __syncthreads();                       // drains vmcnt+lgkmcnt
        #pragma unroll
        for (int kk = 0; kk < 2; ++kk) {
            const int kse = (kk * 32 + g * 8) ^ sx;
            s16x8 af[4], bfj[4];
            #pragma unroll
            for (int i = 0; i < 4; i++) af[i] = *(const s16x8*)&As[(wm * 64 + i * 16 + c) * 64 + kse];
            #pragma unroll
            for (int j = 0; j < 4; j++) bfj[j] = *(const s16x8*)&Bs[(wn * 64 + j * 16 + c) * 64 + kse];
            #pragma unroll
            for (int i = 0; i < 4; i++)
                #pragma unroll
                for (int j = 0; j < 4; j++)
                    acc[i][j] = __builtin_amdgcn_mfma_f32_16x16x32_bf16(af[i], bfj[j], acc[i][j], 0, 0, 0);
        }
    }
    // fused epilogue: v-weighted tanh partial sums for this nt
    float dfv[4], wcv[4], vvj[4];
    #pragma unroll
    for (int j = 0; j < 4; j++) {
        int col = n0 + wn * 64 + j * 16 + c;
        dfv[j] = decfeat[bblk * D2 + col];
        wcv[j] = Wc[col];
        vvj[j] = vvec[col];
    }
    float sAcc[4][4];
    #pragma unroll
    for (int i = 0; i < 4; i++) {
        #pragma unroll
        for (int r = 0; r < 4; r++) {
            const long m = m0 + wm * 64 + i * 16 + g * 4 + r;
            const float covm = cov[m];
            float su = 0.f;
            #pragma unroll
            for (int j = 0; j < 4; j++) {
                float e = acc[i][j][r] + dfv[j] + covm * wcv[j];
                su += tanh_fast(e) * vvj[j];
            }
            su += __shfl_xor(su, 1); su += __shfl_xor(su, 2);
            su += __shfl_xor(su, 4); su += __shfl_xor(su, 8);
            sAcc[i][r] = su;
        }
    }
    if (c == 0) {
        #pragma unroll
        for (int i = 0; i < 4; i++)
            #pragma unroll
            for (int r = 0; r < 4; r++)
                sred[wn][wm * 64 + i * 16 + g * 4 + r] = sAcc[i][r];
    }
    __syncthreads();
    if (tid < 128)
        scorep[(long)nt * MM + m0 + tid] = sred[0][tid] + sred[1][tid] + sred[2][tid] + sred[3][tid];
}

// ---------------------------------------------------------------- K5: softmax + mask renorm
__global__ void k_softmax(const float* __restrict__ scorep, const float* __restrict__ mask,
                          const float* __restrict__ cov, float* __restrict__ att,
                          float* __restrict__ covn) {
    int b = blockIdx.x, tid = threadIdx.x;  // 256 threads
    __shared__ float sm[8];
    float sv[4];
    float mx = -1e30f;
    #pragma unroll
    for (int i = 0; i < 4; i++) {
        long idx = (long)b * TT + tid + 256 * i;
        sv[i] = scorep[idx] + scorep[MM + idx] + scorep[2 * MM + idx] + scorep[3 * MM + idx];
        mx = fmaxf(mx, sv[i]);
    }
    for (int o = 32; o; o >>= 1) mx = fmaxf(mx, __shfl_xor(mx, o));
    if ((tid & 63) == 0) sm[tid >> 6] = mx;
    __syncthreads();
    mx = fmaxf(fmaxf(sm[0], sm[1]), fmaxf(sm[2], sm[3]));
    __syncthreads();
    float e[4]; float s = 0.f;
    #pragma unroll
    for (int i = 0; i < 4; i++) { e[i] = __expf(sv[i] - mx); s += e[i]; }
    for (int o = 32; o; o >>= 1) s += __shfl_xor(s, o);
    if ((tid & 63) == 0) sm[tid >> 6] = s;
    __syncthreads();
    s = sm[0] + sm[1] + sm[2] + sm[3];
    __syncthreads();
    float inv = 1.f / s;
    float am[4]; float s2 = 0.f;
    #pragma unroll
    for (int i = 0; i < 4; i++) { am[i] = e[i] * inv * mask[b * TT + tid + 256 * i]; s2 += am[i]; }
    for (int o = 32; o; o >>= 1) s2 += __shfl_xor(s2, o);
    if ((tid & 63) == 0) sm[tid >> 6] = s2;
    __syncthreads();
    s2 = sm[0] + sm[1] + sm[2] + sm[3];
    float inv2 = 1.f / s2;
    #pragma unroll
    for (int i = 0; i < 4; i++) {
        int t = tid + 256 * i;
        float a = am[i] * inv2;
        att[b * TT + t] = a;
        covn[b * TT + t] = cov[b * TT + t] + a;
    }
}

// ---------------------------------------------------------------- K6: context partials + reduce
__global__ void k_context(const float* __restrict__ enc, const float* __restrict__ att,
                          float* __restrict__ part) {
    int b = blockIdx.x, tc = blockIdx.y;  // grid (32,16)
    int d4 = threadIdx.x;                 // 256 threads -> d = d4*4
    float a0 = 0, a1 = 0, a2 = 0, a3 = 0;
    const float* ab = att + b * TT;
    for (int t = tc * 64; t < tc * 64 + 64; ++t) {
        float a = ab[t];
        f32x4 ev = *(const f32x4*)(enc + ((long)b * TT + t) * D2 + d4 * 4);
        a0 += a * ev[0]; a1 += a * ev[1]; a2 += a * ev[2]; a3 += a * ev[3];
    }
    float* pp = part + (long)tc * BB * D2 + b * D2 + d4 * 4;
    pp[0] = a0; pp[1] = a1; pp[2] = a2; pp[3] = a3;
}

__global__ void k_ctxreduce(const float* __restrict__ part, float* __restrict__ ctx) {
    int i = blockIdx.x * 256 + threadIdx.x;  // 128 blocks
    float s = 0.f;
    #pragma unroll
    for (int p = 0; p < 16; p++) s += part[(long)p * BB * D2 + i];
    ctx[i] = s;
}

// ---------------------------------------------------------------- K7a: p_gen
__global__ void k_pgen(const float* __restrict__ ctx, const float* __restrict__ dechat,
                       const float* __restrict__ xbuf, const float* __restrict__ Wpg,
                       const float* __restrict__ bpg, float* __restrict__ pgen) {
    int b = blockIdx.x, tid = threadIdx.x;  // 256 threads
    __shared__ float sm[8];
    float acc = 0.f;
    for (int k = tid; k < D2; k += 256)
        acc += ctx[b * D2 + k] * Wpg[k] + dechat[b * D2 + k] * Wpg[D2 + k];
    acc += xbuf[b * EE + tid] * Wpg[2 * D2 + tid];
    for (int o = 32; o; o >>= 1) acc += __shfl_xor(acc, o);
    if ((tid & 63) == 0) sm[tid >> 6] = acc;
    __syncthreads();
    if (tid == 0) {
        float t = sm[0] + sm[1] + sm[2] + sm[3];
        pgen[b] = sigmoidf_(t + bpg[0]);
    }
}

// ---------------------------------------------------------------- K7b: hidden = [h1|ctx] @ W_v1 + b_v1
__global__ void k_hidden(const float* __restrict__ h1, const float* __restrict__ ctx,
                         const float* __restrict__ Wv1, const float* __restrict__ bv1,
                         float* __restrict__ hidden, float* __restrict__ hiddenT) {
    __shared__ float xs[1536];
    __shared__ float sred[4][64];
    int b = blockIdx.x, n0 = blockIdx.y * 64;   // grid (32,8)
    int tid = threadIdx.x, nl = tid & 63, ks = tid >> 6;
    for (int i = tid; i < 1536; i += 256)
        xs[i] = (i < 512) ? h1[b * 512 + i] : ctx[b * 1024 + i - 512];
    __syncthreads();
    float acc = 0.f;
    for (int k = ks * 384; k < ks * 384 + 384; ++k)
        acc += xs[k] * Wv1[(long)k * 512 + n0 + nl];
    sred[ks][nl] = acc;
    __syncthreads();
    if (tid < 64) {
        int n = n0 + tid;
        float val = sred[0][tid] + sred[1][tid] + sred[2][tid] + sred[3][tid] + bv1[n];
        hidden[b * 512 + n] = val;
        hiddenT[n * 32 + b] = val;     // [k][b] layout for k_logits s_load path
    }
}

// ---------------------------------------------------------------- K8: logits = hidden @ W_v2 + b_v2
// 1 wave/block, lane = one v column, acc[32] in VGPRs, hiddenT via uniform (scalar) loads.
__global__ __launch_bounds__(64) void k_logits(const float* __restrict__ hiddenT,
                                               const float* __restrict__ Wv2,
                                               const float* __restrict__ bv2,
                                               float* __restrict__ logits) {
    int v = blockIdx.x * 64 + threadIdx.x;
    if (v >= VV) return;
    float acc[32];
    float bv = bv2[v];
    #pragma unroll
    for (int i = 0; i < 32; i++) acc[i] = bv;
    const float* wp = Wv2 + v;
    #pragma unroll 8
    for (int k = 0; k < 512; ++k) {
        float w = wp[(long)k * VV];
        const float* h = hiddenT + k * 32;   // block-uniform -> s_load_dwordx16 x2
        #pragma unroll
        for (int b = 0; b < 32; b++) acc[b] += h[b] * w;
    }
    #pragma unroll
    for (int b = 0; b < 32; b++) logits[(long)b * VV + v] = acc[b];
}

// ---------------------------------------------------------------- K9: per-row max / sumexp
__global__ void k_rowstats(const float* __restrict__ logits, float* __restrict__ stats) {
    int b = blockIdx.x, tid = threadIdx.x;
    __shared__ float sm[8];
    const float* lr = logits + (long)b * VV;
    float mx = -1e30f;
    for (int v = tid; v < VV; v += 256) mx = fmaxf(mx, lr[v]);
    for (int o = 32; o; o >>= 1) mx = fmaxf(mx, __shfl_xor(mx, o));
    if ((tid & 63) == 0) sm[tid >> 6] = mx;
    __syncthreads();
    mx = fmaxf(fmaxf(sm[0], sm[1]), fmaxf(sm[2], sm[3]));
    __syncthreads();
    float s = 0.f;
    for (int v = tid; v < VV; v += 256) s += __expf(lr[v] - mx);
    for (int o = 32; o; o >>= 1) s += __shfl_xor(s, o);
    if ((tid & 63) == 0) sm[tid >> 6] = s;
    __syncthreads();
    if (tid == 0) { stats[2 * b] = mx; stats[2 * b + 1] = sm[0] + sm[1] + sm[2] + sm[3]; }
}

// ---------------------------------------------------------------- K10: final vocab dist
__global__ void k_vocab_final(const float* __restrict__ logits, const float* __restrict__ stats,
                              const float* __restrict__ pgen, const float* __restrict__ extraz,
                              float* __restrict__ out0) {
    int b = blockIdx.x;
    int v = blockIdx.y * 256 + threadIdx.x;
    if (v >= VE) return;
    float r;
    if (v < VV) r = pgen[b] * __expf(logits[(long)b * VV + v] - stats[2 * b]) / stats[2 * b + 1];
    else        r = extraz[b * EXTRA + (v - VV)];
    out0[(long)b * VE + v] = r;
}

// ---------------------------------------------------------------- K11: pointer scatter
__global__ void k_scatter(const int* __restrict__ eiv, const float* __restrict__ att,
                          const float* __restrict__ pgen, float* __restrict__ out0) {
    int b = blockIdx.x;
    int t = blockIdx.y * 256 + threadIdx.x;
    float a = (1.f - pgen[b]) * att[b * TT + t];
    atomicAdd(out0 + (long)b * VE + eiv[b * TT + t], a);
}

// ================================================================ host
extern "C" void kernel_launch(void* const* d_in, const int* in_sizes, int n_in,
                              void* d_out, int out_size, void* d_ws, size_t ws_size,
                              hipStream_t stream) {
    const int*   dec_in = (const int*)d_in[0];
    const float* h0     = (const float*)d_in[1];
    const float* c0     = (const float*)d_in[2];
    const float* enc    = (const float*)d_in[3];
    const float* mask   = (const float*)d_in[4];
    const float* pcv    = (const float*)d_in[5];
    const float* cov    = (const float*)d_in[6];
    const float* extraz = (const float*)d_in[7];
    const int*   eiv    = (const int*)d_in[8];
    /* d_in[9] = step (unused, training path) */
    const float* embt   = (const float*)d_in[10];
    const float* Wgx    = (const float*)d_in[11];
    const float* bgx    = (const float*)d_in[12];
    const float* Wih    = (const float*)d_in[13];
    const float* Whh    = (const float*)d_in[14];
    const float* bih    = (const float*)d_in[15];
    const float* bhh    = (const float*)d_in[16];
    const float* Wh     = (const float*)d_in[17];
    const float* Wc     = (const float*)d_in[18];
    const float* Ws     = (const float*)d_in[19];
    const float* bs     = (const float*)d_in[20];
    const float* vv     = (const float*)d_in[21];
    const float* Wpg    = (const float*)d_in[22];
    const float* bpg    = (const float*)d_in[23];
    const float* Wv1    = (const float*)d_in[24];
    const float* bv1    = (const float*)d_in[25];
    const float* Wv2    = (const float*)d_in[26];
    const float* bv2    = (const float*)d_in[27];

    float* out = (float*)d_out;
    float* out_vd  = out;
    float* out_h1  = out + (long)BB * VE;
    float* out_c1  = out_h1 + BB * DD;
    float* out_ctx = out_c1 + BB * DD;
    float* out_att = out_ctx + BB * D2;
    float* out_cov = out_att + BB * TT;

    char* p = (char*)d_ws;
    unsigned short* whtswz = (unsigned short*)p; p += (size_t)D2 * D2 * 2;      // 2 MB
    float* xbuf    = (float*)p;  p += (size_t)BB * EE * 4;
    float* dechat  = (float*)p;  p += (size_t)BB * D2 * 4;
    float* decfeat = (float*)p;  p += (size_t)BB * D2 * 4;
    float* scorep  = (float*)p;  p += (size_t)4 * MM * 4;                        // 512 KB
    float* pgen    = (float*)p;  p += 256;
    float* hidden  = (float*)p;  p += (size_t)BB * DD * 4;
    float* hiddenT = (float*)p;  p += (size_t)BB * DD * 4;
    float* stats   = (float*)p;  p += 256;
    float* ctxpart = (float*)p;  p += (size_t)16 * BB * D2 * 4;                  // 2 MB
    float* logits  = (float*)p;  p += (size_t)BB * VV * 4;                       // 6.43 MB

    k_transpose_wh<<<dim3(32, 32), dim3(32, 8), 0, stream>>>(Wh, whtswz);
    k_x<<<dim3(BB, 4), 256, 0, stream>>>(dec_in, pcv, embt, Wgx, bgx, xbuf);
    k_lstm<<<dim3(BB, 8), 256, 0, stream>>>(xbuf, h0, c0, Wih, Whh, bih, bhh, out_h1, out_c1, dechat);
    k_decfeat<<<dim3(BB, 16), 256, 0, stream>>>(dechat, Ws, bs, decfeat);
    k_scores<<<1024, 512, 0, stream>>>(enc, whtswz, decfeat, cov, Wc, vv, scorep);
    k_softmax<<<BB, 256, 0, stream>>>(scorep, mask, cov, out_att, out_cov);
    k_context<<<dim3(BB, 16), 256, 0, stream>>>(enc, out_att, ctxpart);
    k_ctxreduce<<<(BB * D2) / 256, 256, 0, stream>>>(ctxpart, out_ctx);
    k_pgen<<<BB, 256, 0, stream>>>(out_ctx, dechat, xbuf, Wpg, bpg, pgen);
    k_hidden<<<dim3(BB, 8), 256, 0, stream>>>(out_h1, out_ctx, Wv1, bv1, hidden, hiddenT);
    k_logits<<<786, 64, 0, stream>>>(hiddenT, Wv2, bv2, logits);
    k_rowstats<<<BB, 256, 0, stream>>>(logits, stats);
    k_vocab_final<<<dim3(BB, (VE + 255) / 256), 256, 0, stream>>>(logits, stats, pgen, extraz, out_vd);
    k_scatter<<<dim3(BB, 4), 256, 0, stream>>>(eiv, out_att, pgen, out_vd);
}